// Round 4
// baseline (198.218 us; speedup 1.0000x reference)
//
#include <hip/hip_runtime.h>
#include <math.h>

#define NROWS 8192
#define NCOLS 32000
#define NF4   (NCOLS / 4)     // 8000 float4 per row
#define NTHREADS 256

typedef float f32x4 __attribute__((ext_vector_type(4)));

// Online logsumexp merge: (m, s) represents log(s) + m == logsumexp so far.
__device__ __forceinline__ void lse_merge(float& m, float& s, float m2, float s2) {
    float nm = fmaxf(m, m2);
    s = s * __expf(m - nm) + s2 * __expf(m2 - nm);
    m = nm;
}

// Chain-independent local tile: (m4, s4) for one float4, then single merge.
__device__ __forceinline__ void lse_tile(float& m, float& s, f32x4 v) {
    float m4 = fmaxf(fmaxf(v.x, v.y), fmaxf(v.z, v.w));
    float s4 = __expf(v.x - m4) + __expf(v.y - m4)
             + __expf(v.z - m4) + __expf(v.w - m4);
    lse_merge(m, s, m4, s4);
}

__global__ __launch_bounds__(NTHREADS) void ce_fused_kernel(
    const float* __restrict__ inputs,
    const int* __restrict__ targets,
    float* __restrict__ out)
{
    const int row = blockIdx.x;
    const float* __restrict__ rowp = inputs + (size_t)row * NCOLS;
    const int tid = threadIdx.x;

    // Thread 0 gathers the target logit early; latency hides under the stream.
    float tlogit = 0.f;
    if (tid == 0) {
        tlogit = rowp[targets[row]];
    }

    // Two independent accumulator chains (even/odd float4 slots).
    float mA = -INFINITY, sA = 0.f;
    float mB = -INFINITY, sB = 0.f;

    const f32x4* __restrict__ rp4 = (const f32x4*)rowp;
    int i = tid;
    for (; i + NTHREADS < NF4; i += 2 * NTHREADS) {
        f32x4 vA = __builtin_nontemporal_load(rp4 + i);
        f32x4 vB = __builtin_nontemporal_load(rp4 + i + NTHREADS);
        lse_tile(mA, sA, vA);
        lse_tile(mB, sB, vB);
    }
    if (i < NF4) {
        lse_tile(mA, sA, __builtin_nontemporal_load(rp4 + i));
    }
    lse_merge(mA, sA, mB, sB);

    // Wave-64 shuffle-down reduce.
    #pragma unroll
    for (int off = 32; off > 0; off >>= 1) {
        float m2 = __shfl_down(mA, off);
        float s2 = __shfl_down(sA, off);
        lse_merge(mA, sA, m2, s2);
    }

    // Cross-wave merge via LDS (4 waves per block).
    __shared__ float sm[NTHREADS / 64];
    __shared__ float ss[NTHREADS / 64];
    const int wave = tid >> 6;
    if ((tid & 63) == 0) { sm[wave] = mA; ss[wave] = sA; }
    __syncthreads();

    if (tid == 0) {
        float M = sm[0], S = ss[0];
        #pragma unroll
        for (int w = 1; w < NTHREADS / 64; ++w) {
            lse_merge(M, S, sm[w], ss[w]);
        }
        float lse = M + __logf(S);
        // loss contribution: (lse - x[t]) / NUM_CLASS, NUM_CLASS = 3.
        // One atomic per block, arrivals staggered -> negligible contention.
        atomicAdd(out, (lse - tlogit) * (1.0f / 3.0f));
    }
}

extern "C" void kernel_launch(void* const* d_in, const int* in_sizes, int n_in,
                              void* d_out, int out_size, void* d_ws, size_t ws_size,
                              hipStream_t stream) {
    const float* inputs  = (const float*)d_in[0];
    const int*   targets = (const int*)d_in[1];
    float* out = (float*)d_out;

    // Zero the accumulator each call (memset node is graph-capturable).
    hipMemsetAsync(out, 0, sizeof(float), stream);
    ce_fused_kernel<<<NROWS, NTHREADS, 0, stream>>>(inputs, targets, out);
}

// Round 5
// 195.228 us; speedup vs baseline: 1.0153x; 1.0153x over previous
//
#include <hip/hip_runtime.h>
#include <math.h>

#define NROWS 8192
#define NCOLS 32000
#define NF4   (NCOLS / 4)     // 8000 float4 per row
#define NTHREADS 256
#define NBLOCKS 2048          // 2048 blocks x 4 waves = 8192 waves = 256 CU x 32 (fully resident)
#define ROWS_PER_BLOCK (NROWS / NBLOCKS)   // 4

typedef float f32x4 __attribute__((ext_vector_type(4)));

// Online logsumexp merge: (m, s) represents log(s) + m == logsumexp so far.
__device__ __forceinline__ void lse_merge(float& m, float& s, float m2, float s2) {
    float nm = fmaxf(m, m2);
    s = s * __expf(m - nm) + s2 * __expf(m2 - nm);
    m = nm;
}

// Chain-independent local tile: (m4, s4) for one float4, then single merge.
__device__ __forceinline__ void lse_tile(float& m, float& s, f32x4 v) {
    float m4 = fmaxf(fmaxf(v.x, v.y), fmaxf(v.z, v.w));
    float s4 = __expf(v.x - m4) + __expf(v.y - m4)
             + __expf(v.z - m4) + __expf(v.w - m4);
    lse_merge(m, s, m4, s4);
}

__global__ __launch_bounds__(NTHREADS) void ce_row_kernel(
    const float* __restrict__ inputs,
    const int* __restrict__ targets,
    float* __restrict__ partials)
{
    const int tid = threadIdx.x;

    #pragma unroll
    for (int k = 0; k < ROWS_PER_BLOCK; ++k) {
        const int row = blockIdx.x + k * NBLOCKS;   // grid sweeps contiguous row band
        const float* __restrict__ rowp = inputs + (size_t)row * NCOLS;

        // Thread 0 gathers the target logit early; latency hides under the stream.
        float tlogit = 0.f;
        if (tid == 0) {
            tlogit = rowp[targets[row]];
        }

        // Two independent accumulator chains (even/odd float4 slots).
        float mA = -INFINITY, sA = 0.f;
        float mB = -INFINITY, sB = 0.f;

        const f32x4* __restrict__ rp4 = (const f32x4*)rowp;
        int i = tid;
        for (; i + NTHREADS < NF4; i += 2 * NTHREADS) {
            f32x4 vA = rp4[i];
            f32x4 vB = rp4[i + NTHREADS];
            lse_tile(mA, sA, vA);
            lse_tile(mB, sB, vB);
        }
        if (i < NF4) {
            lse_tile(mA, sA, rp4[i]);
        }
        lse_merge(mA, sA, mB, sB);

        // Wave-64 shuffle-down reduce.
        #pragma unroll
        for (int off = 32; off > 0; off >>= 1) {
            float m2 = __shfl_down(mA, off);
            float s2 = __shfl_down(sA, off);
            lse_merge(mA, sA, m2, s2);
        }

        // Cross-wave merge via LDS (4 waves per block).
        __shared__ float sm[NTHREADS / 64];
        __shared__ float ss[NTHREADS / 64];
        const int wave = tid >> 6;
        if (k > 0) __syncthreads();   // protect LDS reuse across row iterations
        if ((tid & 63) == 0) { sm[wave] = mA; ss[wave] = sA; }
        __syncthreads();

        if (tid == 0) {
            float M = sm[0], S = ss[0];
            #pragma unroll
            for (int w = 1; w < NTHREADS / 64; ++w) {
                lse_merge(M, S, sm[w], ss[w]);
            }
            float lse = M + __logf(S);
            partials[row] = lse - tlogit;   // = -logp[row, target]  (positive)
        }
    }
}

__global__ __launch_bounds__(NTHREADS) void ce_reduce_kernel(
    const float* __restrict__ partials,
    float* __restrict__ out)
{
    const int tid = threadIdx.x;
    float acc = 0.f;
    for (int i = tid; i < NROWS; i += NTHREADS) acc += partials[i];

    #pragma unroll
    for (int off = 32; off > 0; off >>= 1) acc += __shfl_down(acc, off);

    __shared__ float sa[NTHREADS / 64];
    if ((tid & 63) == 0) sa[tid >> 6] = acc;
    __syncthreads();

    if (tid == 0) {
        float total = 0.f;
        #pragma unroll
        for (int w = 0; w < NTHREADS / 64; ++w) total += sa[w];
        // loss = -sum(logp_picked)/3 = +sum(lse - x[t])/3
        out[0] = total / 3.0f;   // NUM_CLASS = 3
    }
}

extern "C" void kernel_launch(void* const* d_in, const int* in_sizes, int n_in,
                              void* d_out, int out_size, void* d_ws, size_t ws_size,
                              hipStream_t stream) {
    const float* inputs  = (const float*)d_in[0];
    const int*   targets = (const int*)d_in[1];
    float* out = (float*)d_out;
    float* partials = (float*)d_ws;   // NROWS floats << ws_size

    ce_row_kernel<<<NBLOCKS, NTHREADS, 0, stream>>>(inputs, targets, partials);
    ce_reduce_kernel<<<1, NTHREADS, 0, stream>>>(partials, out);
}

// Round 6
// 167.381 us; speedup vs baseline: 1.1842x; 1.1664x over previous
//
#include <hip/hip_runtime.h>
#include <math.h>

#define NROWS 8192
#define NCOLS 32000
#define NF4   (NCOLS / 4)     // 8000 float4 per row
#define NTHREADS 256

typedef float f32x4 __attribute__((ext_vector_type(4)));

// Online logsumexp merge: (m, s) represents log(s) + m == logsumexp so far.
__device__ __forceinline__ void lse_merge(float& m, float& s, float m2, float s2) {
    float nm = fmaxf(m, m2);
    s = s * __expf(m - nm) + s2 * __expf(m2 - nm);
    m = nm;
}

// Chain-independent local tile: (m4, s4) for one float4, then single merge.
__device__ __forceinline__ void lse_tile(float& m, float& s, f32x4 v) {
    float m4 = fmaxf(fmaxf(v.x, v.y), fmaxf(v.z, v.w));
    float s4 = __expf(v.x - m4) + __expf(v.y - m4)
             + __expf(v.z - m4) + __expf(v.w - m4);
    lse_merge(m, s, m4, s4);
}

__global__ __launch_bounds__(NTHREADS) void ce_row_kernel(
    const float* __restrict__ inputs,
    const int* __restrict__ targets,
    float* __restrict__ partials)
{
    const int row = blockIdx.x;
    const float* __restrict__ rowp = inputs + (size_t)row * NCOLS;
    const int tid = threadIdx.x;

    // Thread 0 gathers the target logit early; latency hides under the stream.
    float tlogit = 0.f;
    if (tid == 0) {
        tlogit = rowp[targets[row]];
    }

    // Two independent accumulator chains (even/odd float4 slots).
    float mA = -INFINITY, sA = 0.f;
    float mB = -INFINITY, sB = 0.f;

    // Non-temporal: 1 GB stream with zero reuse -> evict-first policy,
    // skip L2/LLC allocation overhead on the read path.
    const f32x4* __restrict__ rp4 = (const f32x4*)rowp;
    int i = tid;
    for (; i + NTHREADS < NF4; i += 2 * NTHREADS) {
        f32x4 vA = __builtin_nontemporal_load(rp4 + i);
        f32x4 vB = __builtin_nontemporal_load(rp4 + i + NTHREADS);
        lse_tile(mA, sA, vA);
        lse_tile(mB, sB, vB);
    }
    if (i < NF4) {
        lse_tile(mA, sA, __builtin_nontemporal_load(rp4 + i));
    }
    lse_merge(mA, sA, mB, sB);

    // Wave-64 shuffle-down reduce.
    #pragma unroll
    for (int off = 32; off > 0; off >>= 1) {
        float m2 = __shfl_down(mA, off);
        float s2 = __shfl_down(sA, off);
        lse_merge(mA, sA, m2, s2);
    }

    // Cross-wave merge via LDS (4 waves per block).
    __shared__ float sm[NTHREADS / 64];
    __shared__ float ss[NTHREADS / 64];
    const int wave = tid >> 6;
    if ((tid & 63) == 0) { sm[wave] = mA; ss[wave] = sA; }
    __syncthreads();

    if (tid == 0) {
        float M = sm[0], S = ss[0];
        #pragma unroll
        for (int w = 1; w < NTHREADS / 64; ++w) {
            lse_merge(M, S, sm[w], ss[w]);
        }
        float lse = M + __logf(S);
        partials[row] = lse - tlogit;   // = -logp[row, target]  (positive)
    }
}

__global__ __launch_bounds__(NTHREADS) void ce_reduce_kernel(
    const float* __restrict__ partials,
    float* __restrict__ out)
{
    const int tid = threadIdx.x;
    float acc = 0.f;
    for (int i = tid; i < NROWS; i += NTHREADS) acc += partials[i];

    #pragma unroll
    for (int off = 32; off > 0; off >>= 1) acc += __shfl_down(acc, off);

    __shared__ float sa[NTHREADS / 64];
    if ((tid & 63) == 0) sa[tid >> 6] = acc;
    __syncthreads();

    if (tid == 0) {
        float total = 0.f;
        #pragma unroll
        for (int w = 0; w < NTHREADS / 64; ++w) total += sa[w];
        // loss = -sum(logp_picked)/3 = +sum(lse - x[t])/3
        out[0] = total / 3.0f;   // NUM_CLASS = 3
    }
}

extern "C" void kernel_launch(void* const* d_in, const int* in_sizes, int n_in,
                              void* d_out, int out_size, void* d_ws, size_t ws_size,
                              hipStream_t stream) {
    const float* inputs  = (const float*)d_in[0];
    const int*   targets = (const int*)d_in[1];
    float* out = (float*)d_out;
    float* partials = (float*)d_ws;   // NROWS floats << ws_size

    ce_row_kernel<<<NROWS, NTHREADS, 0, stream>>>(inputs, targets, partials);
    ce_reduce_kernel<<<1, NTHREADS, 0, stream>>>(partials, out);
}